// Round 1
// 1236.740 us; speedup vs baseline: 1.3542x; 1.3542x over previous
//
#include <hip/hip_runtime.h>

// Problem constants
#define HID   4096
#define OUTF  4096
#define NTOK  8192          // B*S = 4*2048
#define PROJ_STRIDE 33554432ull  // NTOK*OUTF

typedef int   i32x4 __attribute__((ext_vector_type(4)));
typedef float f32x4 __attribute__((ext_vector_type(4)));

// ---------------------------------------------------------------------------
// Kernel W: int32 weights (values -8..7) -> int8 packed, 4 elems/thread
// ---------------------------------------------------------------------------
__global__ __launch_bounds__(256) void cvt_weights_i8(const int* __restrict__ w,
                                                      char* __restrict__ o,
                                                      int n4) {
    int i = blockIdx.x * blockDim.x + threadIdx.x;
    if (i < n4) {
        int4 v = ((const int4*)w)[i];
        int packed = (v.x & 255) | ((v.y & 255) << 8) |
                     ((v.z & 255) << 16) | (v.w << 24);
        ((int*)o)[i] = packed;
    }
}

// ---------------------------------------------------------------------------
// Kernel T: 64x64 f32 transpose of `left` (once), so transform blocks can
// stage L^T with linear global_load_lds.
// ---------------------------------------------------------------------------
__global__ __launch_bounds__(256) void transpose64(const float* __restrict__ in,
                                                   float* __restrict__ out) {
    int i = blockIdx.x * 256 + threadIdx.x;   // grid 16 * 256 = 4096
    int r = i >> 6, c = i & 63;
    out[c * 64 + r] = in[i];                  // out[l][m] = left[m][l]
}

// ---------------------------------------------------------------------------
// Kernel A: per-token transform + quantize, register-tiled 4x4.
//   thread (tm,tn) = (tid>>4, tid&15) owns XT[4tm..4tm+3][4tn..4tn+3].
//   Stage 1: acc[i][j] = sum_l Lt[l][4tm+i] * X[l][4tn+j]    (2 b128 / 16 FMA)
//   T1^T stored back into Xs with XOR-quad swizzle (q = tm ^ (r&7)) so both
//   the b128 column-writes and stage-2 reads are (near) conflict-free.
//   Stage 2: acc[i][j] = sum_r T1t[r][4tm+i] * R[r][4tn+j]
//   FMA order over l/r identical to previous kernel -> bit-identical xq.
//   Output int8 (for the i8 MFMA GEMM).
// ---------------------------------------------------------------------------
__global__ __launch_bounds__(256) void transform_quant(
    const float* __restrict__ hs, const float* __restrict__ leftT,
    const float* __restrict__ right, char* __restrict__ xq,
    float* __restrict__ ascale) {
    __shared__ __align__(16) float Xs[4096];   // X, then reused as T1^T (swizzled)
    __shared__ __align__(16) float Ls[4096];   // leftT: Ls[l*64+m] = left[m][l]
    __shared__ __align__(16) float Rs[4096];   // right: Rs[r*64+n]
    __shared__ float red[256];

    const int t   = blockIdx.x;
    const int tid = threadIdx.x;
    const int tm  = tid >> 4;
    const int tn  = tid & 15;

    // Stage inputs to LDS: 12 x global_load_lds width-16 per thread.
    {
        const float* src = hs + (size_t)t * HID;
        #pragma unroll
        for (int i = 0; i < 4; i++) {
            int c = tid + i * 256;   // lane-consecutive -> linear LDS dest OK
            __builtin_amdgcn_global_load_lds(
                (const __attribute__((address_space(1))) void*)(src + c * 4),
                (__attribute__((address_space(3))) void*)(Xs + c * 4), 16, 0, 0);
            __builtin_amdgcn_global_load_lds(
                (const __attribute__((address_space(1))) void*)(leftT + c * 4),
                (__attribute__((address_space(3))) void*)(Ls + c * 4), 16, 0, 0);
            __builtin_amdgcn_global_load_lds(
                (const __attribute__((address_space(1))) void*)(right + c * 4),
                (__attribute__((address_space(3))) void*)(Rs + c * 4), 16, 0, 0);
        }
    }
    __syncthreads();

    float acc[4][4];
    #pragma unroll
    for (int i = 0; i < 4; i++)
        #pragma unroll
        for (int j = 0; j < 4; j++) acc[i][j] = 0.f;

    // Stage 1: T1[m][r] = sum_l left[m][l] * X[l][r]
    #pragma unroll 4
    for (int l = 0; l < 64; l++) {
        f32x4 xv = *(const f32x4*)(Xs + l * 64 + tn * 4);
        f32x4 lv = *(const f32x4*)(Ls + l * 64 + tm * 4);
        #pragma unroll
        for (int i = 0; i < 4; i++)
            #pragma unroll
            for (int j = 0; j < 4; j++)
                acc[i][j] = fmaf(lv[i], xv[j], acc[i][j]);
    }
    __syncthreads();                 // all X reads done; reuse Xs as T1^T

    // Write T1^T (column j of the 4x4 tile = 4 consecutive m) with quad swizzle
    #pragma unroll
    for (int j = 0; j < 4; j++) {
        int r = tn * 4 + j;
        int q = tm ^ (r & 7);        // bijective per row; spreads bank quads
        f32x4 col = {acc[0][j], acc[1][j], acc[2][j], acc[3][j]};
        *(f32x4*)(Xs + r * 64 + q * 4) = col;
    }
    __syncthreads();

    // Stage 2: XT[m][n] = sum_r T1[m][r] * right[r][n]
    #pragma unroll
    for (int i = 0; i < 4; i++)
        #pragma unroll
        for (int j = 0; j < 4; j++) acc[i][j] = 0.f;
    #pragma unroll 4
    for (int r = 0; r < 64; r++) {
        f32x4 rv = *(const f32x4*)(Rs + r * 64 + tn * 4);
        int q = tm ^ (r & 7);
        f32x4 tv = *(const f32x4*)(Xs + r * 64 + q * 4);
        #pragma unroll
        for (int i = 0; i < 4; i++)
            #pragma unroll
            for (int j = 0; j < 4; j++)
                acc[i][j] = fmaf(tv[i], rv[j], acc[i][j]);
    }

    // maxabs reduction over the block
    float mx = 0.f;
    #pragma unroll
    for (int i = 0; i < 4; i++)
        #pragma unroll
        for (int j = 0; j < 4; j++) mx = fmaxf(mx, fabsf(acc[i][j]));
    red[tid] = mx;
    __syncthreads();
    for (int s = 128; s > 0; s >>= 1) {
        if (tid < s) red[tid] = fmaxf(red[tid], red[tid + s]);
        __syncthreads();
    }
    float scale = fmaxf(red[0] * (1.0f / 7.0f), 1e-8f);

    // Quantize (true division + rint = numpy round-half-even), pack int8x4
    char* dst = xq + (size_t)t * HID;
    #pragma unroll
    for (int i = 0; i < 4; i++) {
        int packed = 0;
        #pragma unroll
        for (int j = 0; j < 4; j++) {
            float q = rintf(acc[i][j] / scale);
            q = fminf(fmaxf(q, -8.f), 7.f);
            packed |= ((int)q & 255) << (8 * j);
        }
        *(int*)(dst + (tm * 4 + i) * 64 + tn * 4) = packed;
    }
    if (tid == 0) ascale[t] = scale;
}

// ---------------------------------------------------------------------------
// Kernel G: int8 MFMA GEMM (exact), 128x128 tile, BK=64, 256 thr (4 waves 2x2),
// global_load_lds width-16 staging, fused scaling epilogue.
//   out[proj][t][o] = (sum_k xq[t][k] * w[proj][o][k]) * ascale[t] * wscale[o]
// Per-iteration structure identical to the f16 version (16 KB staged,
// 8 ds_read_b128, 16 MFMA) but each MFMA covers K=64 -> 64 iterations not 128.
// ---------------------------------------------------------------------------
#define BM 128
#define BN 128
#define BKI 64

__global__ __launch_bounds__(256) void gemm_qkv(
    const char* __restrict__ xq, const float* __restrict__ ascale,
    const char* __restrict__ w8, const float* __restrict__ sq,
    const float* __restrict__ sk, const float* __restrict__ sv,
    float* __restrict__ out) {
    __shared__ __align__(16) char As[BM * BKI];  // 8 KB, row-major [row][64B]
    __shared__ __align__(16) char Bs[BN * BKI];  // 8 KB

    const int tid  = threadIdx.x;
    const int lane = tid & 63;
    const int wave = tid >> 6;
    const int wr   = wave >> 1;      // 2x2 wave grid, each wave does 64x64
    const int wc   = wave & 1;
    const int ml   = lane & 15;
    const int kq   = lane >> 4;

    const int mb   = blockIdx.x;          // 64 M-tiles
    const int proj = blockIdx.y >> 5;     // 0..2
    const int nb   = blockIdx.y & 31;     // 32 N-tiles

    const char* wp = w8 + (size_t)proj * ((size_t)OUTF * HID);
    const float* wscale = (proj == 0) ? sq : ((proj == 1) ? sk : sv);

    const size_t rowA0 = (size_t)mb * BM;
    const size_t rowB0 = (size_t)nb * BN;

    i32x4 acc[4][4];
    #pragma unroll
    for (int i = 0; i < 4; i++)
        #pragma unroll
        for (int j = 0; j < 4; j++) {
            i32x4 z = {0, 0, 0, 0};
            acc[i][j] = z;
        }

    for (int k0 = 0; k0 < HID; k0 += BKI) {
        // Stage A tile: 128x64 i8 = 8 KB = 512 16B-chunks
        #pragma unroll
        for (int tch = 0; tch < 2; tch++) {
            int c   = tid + tch * 256;
            int row = c >> 2, kc = c & 3;
            const char* g = xq + (rowA0 + row) * HID + k0 + kc * 16;
            __builtin_amdgcn_global_load_lds(
                (const __attribute__((address_space(1))) void*)g,
                (__attribute__((address_space(3))) void*)(As + c * 16), 16, 0, 0);
        }
        #pragma unroll
        for (int tch = 0; tch < 2; tch++) {
            int c   = tid + tch * 256;
            int row = c >> 2, kc = c & 3;
            const char* g = wp + (rowB0 + row) * HID + k0 + kc * 16;
            __builtin_amdgcn_global_load_lds(
                (const __attribute__((address_space(1))) void*)g,
                (__attribute__((address_space(3))) void*)(Bs + c * 16), 16, 0, 0);
        }
        __syncthreads();

        // i8 16x16x64 fragment: lane holds row (lane&15), k = (lane>>4)*16 + j
        i32x4 af[4], bfr[4];
        #pragma unroll
        for (int i = 0; i < 4; i++)
            af[i] = *(const i32x4*)(As + (wr * 64 + i * 16 + ml) * BKI + kq * 16);
        #pragma unroll
        for (int j = 0; j < 4; j++)
            bfr[j] = *(const i32x4*)(Bs + (wc * 64 + j * 16 + ml) * BKI + kq * 16);

        #pragma unroll
        for (int i = 0; i < 4; i++)
            #pragma unroll
            for (int j = 0; j < 4; j++)
                acc[i][j] = __builtin_amdgcn_mfma_i32_16x16x64_i8(
                    af[i], bfr[j], acc[i][j], 0, 0, 0);
        __syncthreads();
    }

    // Epilogue: C/D layout col=lane&15, row=(lane>>4)*4+reg (dtype-independent)
    #pragma unroll
    for (int i = 0; i < 4; i++) {
        #pragma unroll
        for (int rg = 0; rg < 4; rg++) {
            int row  = mb * BM + wr * 64 + i * 16 + kq * 4 + rg;
            float as = ascale[row];
            #pragma unroll
            for (int j = 0; j < 4; j++) {
                int col = nb * BN + wc * 64 + j * 16 + ml;
                out[(size_t)proj * PROJ_STRIDE + (size_t)row * OUTF + col] =
                    (float)acc[i][j][rg] * as * wscale[col];
            }
        }
    }
}

// ---------------------------------------------------------------------------
// Launch
// ---------------------------------------------------------------------------
extern "C" void kernel_launch(void* const* d_in, const int* in_sizes, int n_in,
                              void* d_out, int out_size, void* d_ws, size_t ws_size,
                              hipStream_t stream) {
    const float* hs    = (const float*)d_in[0];
    const float* left  = (const float*)d_in[1];
    const float* right = (const float*)d_in[2];
    const int*   wq    = (const int*)d_in[3];
    const float* sq    = (const float*)d_in[4];
    const int*   wk    = (const int*)d_in[5];
    const float* sk    = (const float*)d_in[6];
    const int*   wv    = (const int*)d_in[7];
    const float* sv    = (const float*)d_in[8];
    float* out = (float*)d_out;

    // Workspace layout
    //   xq8    : NTOK*HID i8        = 33,554,432 B
    //   ascale : NTOK f32           =     32,768 B
    //   w8     : 3*OUTF*HID i8      = 50,331,648 B
    //   leftT  : 64*64 f32          =     16,384 B
    char*  xq8  = (char*)d_ws;
    float* ascl = (float*)((char*)d_ws + 33554432ull);
    char*  w8   = (char*)d_ws + 33587200ull;
    float* ltT  = (float*)((char*)d_ws + 83918848ull);

    const int nW = OUTF * HID;       // per-projection weight elements
    const int n4 = nW / 4;
    dim3 cblk(256), cgrd((n4 + 255) / 256);
    cvt_weights_i8<<<cgrd, cblk, 0, stream>>>(wq, w8 + 0ull * (size_t)nW, n4);
    cvt_weights_i8<<<cgrd, cblk, 0, stream>>>(wk, w8 + 1ull * (size_t)nW, n4);
    cvt_weights_i8<<<cgrd, cblk, 0, stream>>>(wv, w8 + 2ull * (size_t)nW, n4);

    transpose64<<<dim3(16), dim3(256), 0, stream>>>(left, ltT);

    transform_quant<<<dim3(NTOK), dim3(256), 0, stream>>>(hs, ltT, right, xq8, ascl);

    gemm_qkv<<<dim3(NTOK / BM, 3 * (OUTF / BN)), dim3(256), 0, stream>>>(
        xq8, ascl, w8, sq, sk, sv, out);
}

// Round 2
// 1192.995 us; speedup vs baseline: 1.4039x; 1.0367x over previous
//
#include <hip/hip_runtime.h>

// Problem constants
#define HID   4096
#define OUTF  4096
#define NTOK  8192          // B*S = 4*2048
#define PROJ_STRIDE 33554432ull  // NTOK*OUTF

typedef int   i32x4 __attribute__((ext_vector_type(4)));
typedef float f32x4 __attribute__((ext_vector_type(4)));

// ---------------------------------------------------------------------------
// Kernel W: int32 weights (values -8..7) -> int8 packed, 4 elems/thread
// ---------------------------------------------------------------------------
__global__ __launch_bounds__(256) void cvt_weights_i8(const int* __restrict__ w,
                                                      char* __restrict__ o,
                                                      int n4) {
    int i = blockIdx.x * blockDim.x + threadIdx.x;
    if (i < n4) {
        int4 v = ((const int4*)w)[i];
        int packed = (v.x & 255) | ((v.y & 255) << 8) |
                     ((v.z & 255) << 16) | (v.w << 24);
        ((int*)o)[i] = packed;
    }
}

// ---------------------------------------------------------------------------
// Kernel T: 64x64 f32 transpose of `left` (once)
// ---------------------------------------------------------------------------
__global__ __launch_bounds__(256) void transpose64(const float* __restrict__ in,
                                                   float* __restrict__ out) {
    int i = blockIdx.x * 256 + threadIdx.x;   // grid 16 * 256 = 4096
    int r = i >> 6, c = i & 63;
    out[c * 64 + r] = in[i];                  // out[l][m] = left[m][l]
}

// ---------------------------------------------------------------------------
// Kernel A: per-token transform + quantize (unchanged from round 1 —
// kept identical so next round's rocprof exposes its true counters).
// ---------------------------------------------------------------------------
__global__ __launch_bounds__(256) void transform_quant(
    const float* __restrict__ hs, const float* __restrict__ leftT,
    const float* __restrict__ right, char* __restrict__ xq,
    float* __restrict__ ascale) {
    __shared__ __align__(16) float Xs[4096];   // X, then reused as T1^T (swizzled)
    __shared__ __align__(16) float Ls[4096];   // leftT: Ls[l*64+m] = left[m][l]
    __shared__ __align__(16) float Rs[4096];   // right: Rs[r*64+n]
    __shared__ float red[256];

    const int t   = blockIdx.x;
    const int tid = threadIdx.x;
    const int tm  = tid >> 4;
    const int tn  = tid & 15;

    {
        const float* src = hs + (size_t)t * HID;
        #pragma unroll
        for (int i = 0; i < 4; i++) {
            int c = tid + i * 256;
            __builtin_amdgcn_global_load_lds(
                (const __attribute__((address_space(1))) void*)(src + c * 4),
                (__attribute__((address_space(3))) void*)(Xs + c * 4), 16, 0, 0);
            __builtin_amdgcn_global_load_lds(
                (const __attribute__((address_space(1))) void*)(leftT + c * 4),
                (__attribute__((address_space(3))) void*)(Ls + c * 4), 16, 0, 0);
            __builtin_amdgcn_global_load_lds(
                (const __attribute__((address_space(1))) void*)(right + c * 4),
                (__attribute__((address_space(3))) void*)(Rs + c * 4), 16, 0, 0);
        }
    }
    __syncthreads();

    float acc[4][4];
    #pragma unroll
    for (int i = 0; i < 4; i++)
        #pragma unroll
        for (int j = 0; j < 4; j++) acc[i][j] = 0.f;

    #pragma unroll 4
    for (int l = 0; l < 64; l++) {
        f32x4 xv = *(const f32x4*)(Xs + l * 64 + tn * 4);
        f32x4 lv = *(const f32x4*)(Ls + l * 64 + tm * 4);
        #pragma unroll
        for (int i = 0; i < 4; i++)
            #pragma unroll
            for (int j = 0; j < 4; j++)
                acc[i][j] = fmaf(lv[i], xv[j], acc[i][j]);
    }
    __syncthreads();

    #pragma unroll
    for (int j = 0; j < 4; j++) {
        int r = tn * 4 + j;
        int q = tm ^ (r & 7);
        f32x4 col = {acc[0][j], acc[1][j], acc[2][j], acc[3][j]};
        *(f32x4*)(Xs + r * 64 + q * 4) = col;
    }
    __syncthreads();

    #pragma unroll
    for (int i = 0; i < 4; i++)
        #pragma unroll
        for (int j = 0; j < 4; j++) acc[i][j] = 0.f;
    #pragma unroll 4
    for (int r = 0; r < 64; r++) {
        f32x4 rv = *(const f32x4*)(Rs + r * 64 + tn * 4);
        int q = tm ^ (r & 7);
        f32x4 tv = *(const f32x4*)(Xs + r * 64 + q * 4);
        #pragma unroll
        for (int i = 0; i < 4; i++)
            #pragma unroll
            for (int j = 0; j < 4; j++)
                acc[i][j] = fmaf(tv[i], rv[j], acc[i][j]);
    }

    float mx = 0.f;
    #pragma unroll
    for (int i = 0; i < 4; i++)
        #pragma unroll
        for (int j = 0; j < 4; j++) mx = fmaxf(mx, fabsf(acc[i][j]));
    red[tid] = mx;
    __syncthreads();
    for (int s = 128; s > 0; s >>= 1) {
        if (tid < s) red[tid] = fmaxf(red[tid], red[tid + s]);
        __syncthreads();
    }
    float scale = fmaxf(red[0] * (1.0f / 7.0f), 1e-8f);

    char* dst = xq + (size_t)t * HID;
    #pragma unroll
    for (int i = 0; i < 4; i++) {
        int packed = 0;
        #pragma unroll
        for (int j = 0; j < 4; j++) {
            float q = rintf(acc[i][j] / scale);
            q = fminf(fmaxf(q, -8.f), 7.f);
            packed |= ((int)q & 255) << (8 * j);
        }
        *(int*)(dst + (tm * 4 + i) * 64 + tn * 4) = packed;
    }
    if (tid == 0) ascale[t] = scale;
}

// ---------------------------------------------------------------------------
// Kernel G: i8 MFMA GEMM, 8-phase 256x256 template (T2+T3+T4+T5 port).
//   BM=BN=256, BK=128 i8 (128 B/row — byte-isomorphic to the bf16 template's
//   BK=64). 512 thr = 8 waves (2M x 4N); per-wave output 128x64 as two 64-row
//   strips (qm) x two 32-col strips (qn) so phase quadrants map to data halves.
//   LDS 128 KiB: [2 dbuf][2 half][16 KiB] for A and B; Ktile k -> buf k&1.
//   T2: (ml&7)<<4 XOR swizzle, both-sides (pre-swizzled global source in
//   STAGE + swizzled ds_read address). T4: vmcnt(4) gates at phases 3/7
//   (vmcnt(0) on final iter to drain). T5: setprio around the 16-MFMA cluster.
//   Half-tile ledger: each half is overwritten strictly >=1 barrier-separated
//   phase after its last read (retire A0@p1,B0@p2,A1@p3,B1@p3; refill
//   @p2,p3,p4,p5; buf1 retire A1@p7,B1@p7; refill @p0',p1').
// ---------------------------------------------------------------------------
#define BM 256
#define BN 256
#define BKI 128
#define NIT 16   // (HID/BKI)/2

#define STAGE(GB, R0, KT, DREG)                                              \
  { _Pragma("unroll") for (int jj_ = 0; jj_ < 2; jj_++) {                    \
      const int c_  = jj_ * 512 + tid;                                       \
      const int rh_ = c_ >> 3;                                               \
      const int sw_ = ((c_ ^ rh_) & 7) << 4;                                 \
      const char* g_ = (GB) + (size_t)((R0) + rh_) * HID + (KT) * BKI + sw_; \
      __builtin_amdgcn_global_load_lds(                                      \
          (const __attribute__((address_space(1))) void*)g_,                 \
          (__attribute__((address_space(3))) void*)((DREG) + c_ * 16),       \
          16, 0, 0);                                                         \
  } }

#define PHASE(QM, QN, BUF, PF_STMT, GATE_STMT)                               \
  {                                                                          \
    const char* Ab_ = As + (BUF) * 32768 + (QM) * 16384;                     \
    const char* Bb_ = Bs + (BUF) * 32768 + (QN) * 16384;                     \
    i32x4 a0_[4], a1_[4], b0_[2], b1_[2];                                    \
    _Pragma("unroll") for (int ii = 0; ii < 4; ii++) {                       \
      const int rh = wr * 64 + ii * 16 + ml;                                 \
      const int bs = rh * 128 + kq * 16;                                     \
      a0_[ii] = *(const i32x4*)(Ab_ + ((bs) ^ xr));                          \
      a1_[ii] = *(const i32x4*)(Ab_ + ((bs + 64) ^ xr));                     \
    }                                                                        \
    _Pragma("unroll") for (int jj = 0; jj < 2; jj++) {                       \
      const int rh = wc * 32 + jj * 16 + ml;                                 \
      const int bs = rh * 128 + kq * 16;                                     \
      b0_[jj] = *(const i32x4*)(Bb_ + ((bs) ^ xr));                          \
      b1_[jj] = *(const i32x4*)(Bb_ + ((bs + 64) ^ xr));                     \
    }                                                                        \
    PF_STMT;                                                                 \
    GATE_STMT;                                                               \
    __builtin_amdgcn_sched_barrier(0);                                       \
    __builtin_amdgcn_s_barrier();                                            \
    __builtin_amdgcn_s_setprio(1);                                           \
    _Pragma("unroll") for (int ii = 0; ii < 4; ii++)                         \
      _Pragma("unroll") for (int jj = 0; jj < 2; jj++) {                     \
        acc[(QM)*4+ii][(QN)*2+jj] = __builtin_amdgcn_mfma_i32_16x16x64_i8(   \
            a0_[ii], b0_[jj], acc[(QM)*4+ii][(QN)*2+jj], 0, 0, 0);           \
        acc[(QM)*4+ii][(QN)*2+jj] = __builtin_amdgcn_mfma_i32_16x16x64_i8(   \
            a1_[ii], b1_[jj], acc[(QM)*4+ii][(QN)*2+jj], 0, 0, 0);           \
      }                                                                      \
    __builtin_amdgcn_s_setprio(0);                                           \
    __builtin_amdgcn_sched_barrier(0);                                       \
    __builtin_amdgcn_s_barrier();                                            \
    __builtin_amdgcn_sched_barrier(0);                                       \
  }

#define GATE4 if (pf) { asm volatile("s_waitcnt vmcnt(4)" ::: "memory"); } \
              else    { asm volatile("s_waitcnt vmcnt(0)" ::: "memory"); }

__global__ __launch_bounds__(512, 2) void gemm_qkv(
    const char* __restrict__ xq, const float* __restrict__ ascale,
    const char* __restrict__ w8, const float* __restrict__ sq,
    const float* __restrict__ sk, const float* __restrict__ sv,
    float* __restrict__ out) {
    __shared__ __align__(16) char As[2 * 2 * 16384];   // 64 KB
    __shared__ __align__(16) char Bs[2 * 2 * 16384];   // 64 KB

    const int tid  = threadIdx.x;
    const int lane = tid & 63;
    const int wave = tid >> 6;
    const int wr   = wave >> 2;     // 0..1  (M strip pair)
    const int wc   = wave & 3;      // 0..3  (N strip quad)
    const int ml   = lane & 15;
    const int kq   = lane >> 4;
    const int xr   = (ml & 7) << 4; // T2 swizzle term (rh&7 == ml&7 everywhere)

    // XCD-aware bijective swizzle: nwg = 1536 = 8 * 192
    const int wg   = blockIdx.x;
    const int swz  = (wg & 7) * 192 + (wg >> 3);
    const int proj = swz >> 9;      // 0..2
    const int rr   = swz & 511;
    const int nb   = rr >> 5;       // 0..15  (mb fastest -> shared B panel in L2)
    const int mb   = rr & 31;       // 0..31

    const char* Ag = xq;
    const char* Bg = w8 + (size_t)proj * ((size_t)OUTF * HID);
    const float* wscale = (proj == 0) ? sq : ((proj == 1) ? sk : sv);

    const size_t rowA0 = (size_t)mb * BM;
    const size_t rowB0 = (size_t)nb * BN;

    i32x4 acc[8][4];
    #pragma unroll
    for (int i = 0; i < 8; i++)
        #pragma unroll
        for (int j = 0; j < 4; j++) {
            i32x4 z = {0, 0, 0, 0};
            acc[i][j] = z;
        }

    // Prologue: K0 all 4 halves + K1.A0 + K1.B0; leave 2 halves in flight.
    STAGE(Ag, rowA0,       0, As + 0);
    STAGE(Bg, rowB0,       0, Bs + 0);
    STAGE(Ag, rowA0 + 128, 0, As + 16384);
    STAGE(Bg, rowB0 + 128, 0, Bs + 16384);
    STAGE(Ag, rowA0,       1, As + 32768);
    STAGE(Bg, rowB0,       1, Bs + 32768);
    asm volatile("s_waitcnt vmcnt(4)" ::: "memory");   // K0 landed
    __builtin_amdgcn_s_barrier();

    for (int t = 0; t < NIT; t++) {
        const bool pf = (t < NIT - 1);
        const int k1 = 2 * t + 1, k2 = 2 * t + 2, k3 = 2 * t + 3;
        // phases 0-3: Ktile 2t (buf0); phases 4-7: Ktile 2t+1 (buf1)
        PHASE(0, 0, 0, STAGE(Ag, rowA0 + 128, k1, As + 32768 + 16384), ;)
        PHASE(0, 1, 0, STAGE(Bg, rowB0 + 128, k1, Bs + 32768 + 16384), ;)
        PHASE(1, 0, 0, if (pf) STAGE(Ag, rowA0,       k2, As + 0), ;)
        PHASE(1, 1, 0, if (pf) STAGE(Bg, rowB0,       k2, Bs + 0), GATE4)
        PHASE(0, 0, 1, if (pf) STAGE(Ag, rowA0 + 128, k2, As + 16384), ;)
        PHASE(0, 1, 1, if (pf) STAGE(Bg, rowB0 + 128, k2, Bs + 16384), ;)
        PHASE(1, 0, 1, if (pf) STAGE(Ag, rowA0,       k3, As + 32768), ;)
        PHASE(1, 1, 1, if (pf) STAGE(Bg, rowB0,       k3, Bs + 32768), GATE4)
    }

    // Epilogue: C/D layout col=ml, row=kq*4+rg (dtype-independent).
    // row strips: (i>>2)*128 + wr*64 + (i&3)*16 ; col strips: (j>>1)*128 + wc*32 + (j&1)*16
    #pragma unroll
    for (int i = 0; i < 8; i++) {
        const int row = (int)rowA0 + (i >> 2) * 128 + wr * 64 + (i & 3) * 16 + kq * 4;
        #pragma unroll
        for (int rg = 0; rg < 4; rg++) {
            const float as = ascale[row + rg];
            float* orow = out + (size_t)proj * PROJ_STRIDE + (size_t)(row + rg) * OUTF;
            #pragma unroll
            for (int j = 0; j < 4; j++) {
                const int col = (int)rowB0 + (j >> 1) * 128 + wc * 32 + (j & 1) * 16 + ml;
                orow[col] = (float)acc[i][j][rg] * as * wscale[col];
            }
        }
    }
}

// ---------------------------------------------------------------------------
// Launch
// ---------------------------------------------------------------------------
extern "C" void kernel_launch(void* const* d_in, const int* in_sizes, int n_in,
                              void* d_out, int out_size, void* d_ws, size_t ws_size,
                              hipStream_t stream) {
    const float* hs    = (const float*)d_in[0];
    const float* left  = (const float*)d_in[1];
    const float* right = (const float*)d_in[2];
    const int*   wq    = (const int*)d_in[3];
    const float* sq    = (const float*)d_in[4];
    const int*   wk    = (const int*)d_in[5];
    const float* sk    = (const float*)d_in[6];
    const int*   wv    = (const int*)d_in[7];
    const float* sv    = (const float*)d_in[8];
    float* out = (float*)d_out;

    // Workspace layout
    //   xq8    : NTOK*HID i8        = 33,554,432 B
    //   ascale : NTOK f32           =     32,768 B
    //   w8     : 3*OUTF*HID i8      = 50,331,648 B
    //   leftT  : 64*64 f32          =     16,384 B
    char*  xq8  = (char*)d_ws;
    float* ascl = (float*)((char*)d_ws + 33554432ull);
    char*  w8   = (char*)d_ws + 33587200ull;
    float* ltT  = (float*)((char*)d_ws + 83918848ull);

    const int nW = OUTF * HID;
    const int n4 = nW / 4;
    dim3 cblk(256), cgrd((n4 + 255) / 256);
    cvt_weights_i8<<<cgrd, cblk, 0, stream>>>(wq, w8 + 0ull * (size_t)nW, n4);
    cvt_weights_i8<<<cgrd, cblk, 0, stream>>>(wk, w8 + 1ull * (size_t)nW, n4);
    cvt_weights_i8<<<cgrd, cblk, 0, stream>>>(wv, w8 + 2ull * (size_t)nW, n4);

    transpose64<<<dim3(16), dim3(256), 0, stream>>>(left, ltT);

    transform_quant<<<dim3(NTOK), dim3(256), 0, stream>>>(hs, ltT, right, xq8, ascl);

    gemm_qkv<<<dim3((NTOK / BM) * (OUTF / BN) * 3), dim3(512), 0, stream>>>(
        xq8, ascl, w8, sq, sk, sv, out);
}